// Round 1
// baseline (102.571 us; speedup 1.0000x reference)
//
#include <hip/hip_runtime.h>
#include <math.h>

#define NEG_INF_F (-9000000000000000.0f)
#define ALPHA_F 0.2f

static constexpr int D = 64;
static constexpr int M = 40;

// ---------------------------------------------------------------------------
// Pre-kernel: wa1[d] = sum_e W[d][e]*a[e], wa2[d] = sum_e W[d][e]*a[D+e]
// One block of 64 threads; writes 128 floats into workspace.
// ---------------------------------------------------------------------------
__global__ void precompute_wa(const float* __restrict__ W,
                              const float* __restrict__ a,
                              float* __restrict__ ws) {
    int d = threadIdx.x;  // 0..63
    const float* wrow = W + d * D;
    float acc1 = 0.f, acc2 = 0.f;
#pragma unroll 8
    for (int e = 0; e < D; ++e) {
        float w = wrow[e];
        acc1 += w * a[e];
        acc2 += w * a[D + e];
    }
    ws[d] = acc1;
    ws[D + d] = acc2;
}

// ---------------------------------------------------------------------------
// Main kernel: one wave (64 lanes) per row n. 4 waves per 256-thread block.
// ---------------------------------------------------------------------------
__launch_bounds__(256)
__global__ void kgat_kernel(const float* __restrict__ item,
                            const float* __restrict__ ent,
                            const int* __restrict__ adj,
                            const float* __restrict__ wa,   // ws: wa1[64], wa2[64]
                            float* __restrict__ out,
                            int N) {
    __shared__ float lds_ent[4][M * D];   // 4 x 10240 B
    __shared__ float lds_e[4][48];        // per-wave e / weight buffer

    const int wave = threadIdx.x >> 6;
    const int lane = threadIdx.x & 63;
    const int n = blockIdx.x * 4 + wave;
    if (n >= N) return;

    float* my_ent = lds_ent[wave];
    float* my_e   = lds_e[wave];

    const float* row = ent + (size_t)n * (M * D);

    // per-lane constants
    const float wa1_l = wa[lane];
    const int   q     = lane & 15;   // sub-group index within 16-lane group
    const int   grp   = lane >> 4;   // 0..3
    const float4 wa2v = *reinterpret_cast<const float4*>(wa + D + q * 4);
    const float itemv = item[(size_t)n * D + lane];

    // s_item = item[n] . wa1   (full-wave reduce)
    float s_item = itemv * wa1_l;
#pragma unroll
    for (int off = 32; off; off >>= 1) s_item += __shfl_xor(s_item, off, 64);

    // Phase 1: stream entity row -> LDS, fused partial dot with wa2.
    // iteration i, lane l covers elements [i*256 + l*4, +4) of the row:
    //   m = i*4 + (l>>4), d = (l&15)*4
#pragma unroll
    for (int i = 0; i < 10; ++i) {
        const int idx = i * 256 + lane * 4;
        float4 v = *reinterpret_cast<const float4*>(row + idx);
        *reinterpret_cast<float4*>(my_ent + idx) = v;
        float p = v.x * wa2v.x + v.y * wa2v.y + v.z * wa2v.z + v.w * wa2v.w;
        // reduce over the 16-lane group (offsets < 16 stay in-group)
        p += __shfl_xor(p, 1, 64);
        p += __shfl_xor(p, 2, 64);
        p += __shfl_xor(p, 4, 64);
        p += __shfl_xor(p, 8, 64);
        if (q == 0) my_e[i * 4 + grp] = p;   // m = i*4 + grp
    }

    // Phase 2: softmax over m (lane m holds e[m]); lanes >= M inert.
    float ev;
    if (lane < M) {
        float e = s_item + my_e[lane];
        e = (e > 0.f) ? e : ALPHA_F * e;                 // leaky relu
        const int am = adj[(size_t)n * M + lane];
        ev = (am > 0) ? e : NEG_INF_F;                   // mask
    } else {
        ev = -INFINITY;                                  // exact zero weight
    }
    float mx = ev;
#pragma unroll
    for (int off = 32; off; off >>= 1) mx = fmaxf(mx, __shfl_xor(mx, off, 64));
    const float ex = __expf(ev - mx);
    float sum = ex;
#pragma unroll
    for (int off = 32; off; off >>= 1) sum += __shfl_xor(sum, off, 64);
    const float wgt = ex / sum;
    if (lane < M) my_e[lane] = wgt;

    // Phase 3: agg[d] = sum_m w[m] * ent[m][d]  (lane = d)
    float agg = 0.f;
#pragma unroll
    for (int m = 0; m < M; ++m) {
        agg += my_e[m] * my_ent[m * D + lane];
    }
    out[(size_t)n * D + lane] = agg + itemv;
}

// ---------------------------------------------------------------------------
extern "C" void kernel_launch(void* const* d_in, const int* in_sizes, int n_in,
                              void* d_out, int out_size, void* d_ws, size_t ws_size,
                              hipStream_t stream) {
    const float* item = (const float*)d_in[0];   // (N, 64)
    const float* ent  = (const float*)d_in[1];   // (N, 40, 64)
    const int*   adj  = (const int*)d_in[2];     // (N, 40)
    const float* W    = (const float*)d_in[3];   // (64, 64)
    const float* a    = (const float*)d_in[4];   // (128, 1)
    float* out = (float*)d_out;
    float* ws  = (float*)d_ws;                   // 128 floats used

    const int N = in_sizes[0] / D;

    precompute_wa<<<1, 64, 0, stream>>>(W, a, ws);

    const int blocks = (N + 3) / 4;
    kgat_kernel<<<blocks, 256, 0, stream>>>(item, ent, adj, ws, out, N);
}

// Round 2
// 61.580 us; speedup vs baseline: 1.6657x; 1.6657x over previous
//
#include <hip/hip_runtime.h>
#include <math.h>

#define NEG_INF_F (-9000000000000000.0f)
#define ALPHA_F 0.2f

static constexpr int D = 64;
static constexpr int M = 40;

// ---------------------------------------------------------------------------
// Pre-kernel: wa1[d] = sum_e W[d][e]*a[e], wa2[d] = sum_e W[d][e]*a[D+e]
// ---------------------------------------------------------------------------
__global__ void precompute_wa(const float* __restrict__ W,
                              const float* __restrict__ a,
                              float* __restrict__ ws) {
    int d = threadIdx.x;  // 0..63
    const float* wrow = W + d * D;
    float acc1 = 0.f, acc2 = 0.f;
#pragma unroll 8
    for (int e = 0; e < D; ++e) {
        float w = wrow[e];
        acc1 += w * a[e];
        acc2 += w * a[D + e];
    }
    ws[d] = acc1;
    ws[D + d] = acc2;
}

// ---------------------------------------------------------------------------
// Main kernel: one wave per row n; entity row lives in registers (10x float4).
// Lane layout: q = lane&15 (d-chunk q*4..q*4+3), grp = lane>>4.
// v[i] holds ent[n, m = i*4+grp, d = q*4 .. q*4+3].
// ---------------------------------------------------------------------------
__launch_bounds__(256)
__global__ void kgat_kernel(const float* __restrict__ item,
                            const float* __restrict__ ent,
                            const int* __restrict__ adj,
                            const float* __restrict__ wa,   // wa1[64], wa2[64]
                            float* __restrict__ out,
                            int N) {
    __shared__ float lds_e[4][M];   // 160 B per wave: e[m] scatter buffer

    const int wave = threadIdx.x >> 6;
    const int lane = threadIdx.x & 63;
    const int n = blockIdx.x * 4 + wave;
    if (n >= N) return;

    float* my_e = lds_e[wave];
    const int q   = lane & 15;
    const int grp = lane >> 4;

    const float* row = ent + (size_t)n * (M * D);

    // ---- issue all global loads up front (independent, deep MLP) ----
    float4 v[10];
#pragma unroll
    for (int i = 0; i < 10; ++i) {
        v[i] = *reinterpret_cast<const float4*>(row + i * 256 + lane * 4);
    }
    const float4 itv  = *reinterpret_cast<const float4*>(item + (size_t)n * D + q * 4);
    const int    am   = (lane < M) ? adj[(size_t)n * M + lane] : 0;
    const float4 wa1v = *reinterpret_cast<const float4*>(wa + q * 4);
    const float4 wa2v = *reinterpret_cast<const float4*>(wa + D + q * 4);

    // ---- s_item = item[n] . wa1  (16-lane group covers all of D; all groups
    //      compute the same full dot) ----
    float s_item = itv.x * wa1v.x + itv.y * wa1v.y + itv.z * wa1v.z + itv.w * wa1v.w;
    s_item += __shfl_xor(s_item, 1, 64);
    s_item += __shfl_xor(s_item, 2, 64);
    s_item += __shfl_xor(s_item, 4, 64);
    s_item += __shfl_xor(s_item, 8, 64);

    // ---- e[m] = ent[n,m,:] . wa2 ; scatter to LDS (lane m reads it back) ----
#pragma unroll
    for (int i = 0; i < 10; ++i) {
        float p = v[i].x * wa2v.x + v[i].y * wa2v.y + v[i].z * wa2v.z + v[i].w * wa2v.w;
        p += __shfl_xor(p, 1, 64);
        p += __shfl_xor(p, 2, 64);
        p += __shfl_xor(p, 4, 64);
        p += __shfl_xor(p, 8, 64);
        if (q == 0) my_e[i * 4 + grp] = p;   // m = i*4 + grp
    }

    // ---- softmax over m (lane m holds e[m]); lanes >= M contribute 0 ----
    float ev;
    if (lane < M) {
        float e = s_item + my_e[lane];
        e = (e > 0.f) ? e : ALPHA_F * e;          // leaky relu
        ev = (am > 0) ? e : NEG_INF_F;            // adjacency mask
    } else {
        ev = -INFINITY;
    }
    float mx = ev;
#pragma unroll
    for (int off = 32; off; off >>= 1) mx = fmaxf(mx, __shfl_xor(mx, off, 64));
    const float ex = __expf(ev - mx);
    float sum = ex;
#pragma unroll
    for (int off = 32; off; off >>= 1) sum += __shfl_xor(sum, off, 64);
    const float wgt = ex / sum;                   // lane m: attention[n,m]

    // ---- agg[d] = sum_m w[m] * ent[n,m,d], from registers ----
    float4 acc = make_float4(0.f, 0.f, 0.f, 0.f);
#pragma unroll
    for (int i = 0; i < 10; ++i) {
        const float w = __shfl(wgt, i * 4 + grp, 64);   // m = i*4+grp < 40
        acc.x += w * v[i].x;
        acc.y += w * v[i].y;
        acc.z += w * v[i].z;
        acc.w += w * v[i].w;
    }
    // reduce across the 4 groups (lanes q, q+16, q+32, q+48)
#pragma unroll
    for (int off = 16; off <= 32; off <<= 1) {
        acc.x += __shfl_xor(acc.x, off, 64);
        acc.y += __shfl_xor(acc.y, off, 64);
        acc.z += __shfl_xor(acc.z, off, 64);
        acc.w += __shfl_xor(acc.w, off, 64);
    }
    if (grp == 0) {
        float4 o = make_float4(acc.x + itv.x, acc.y + itv.y,
                               acc.z + itv.z, acc.w + itv.w);
        *reinterpret_cast<float4*>(out + (size_t)n * D + q * 4) = o;
    }
}

// ---------------------------------------------------------------------------
extern "C" void kernel_launch(void* const* d_in, const int* in_sizes, int n_in,
                              void* d_out, int out_size, void* d_ws, size_t ws_size,
                              hipStream_t stream) {
    const float* item = (const float*)d_in[0];   // (N, 64)
    const float* ent  = (const float*)d_in[1];   // (N, 40, 64)
    const int*   adj  = (const int*)d_in[2];     // (N, 40)
    const float* W    = (const float*)d_in[3];   // (64, 64)
    const float* a    = (const float*)d_in[4];   // (128, 1)
    float* out = (float*)d_out;
    float* ws  = (float*)d_ws;                   // 128 floats used

    const int N = in_sizes[0] / D;

    precompute_wa<<<1, 64, 0, stream>>>(W, a, ws);

    const int blocks = (N + 3) / 4;
    kgat_kernel<<<blocks, 256, 0, stream>>>(item, ent, adj, ws, out, N);
}